// Round 6
// baseline (194.071 us; speedup 1.0000x reference)
//
#include <hip/hip_runtime.h>

typedef __bf16 bf16;
typedef __bf16 bf16x8 __attribute__((ext_vector_type(8)));
typedef __bf16 bf16x4 __attribute__((ext_vector_type(4)));
typedef float  f32x4  __attribute__((ext_vector_type(4)));

#define D_MODEL 1024
#define S_LEN   2048
#define NHEAD   16
#define DHEAD   64
#define BATCH   2
#define MROWS   (BATCH * S_LEN)   // 4096

// 0.125 (1/sqrt(dhead)) * log2(e): Q pre-scaled so softmax runs in exp2 domain
#define QSCALE 0.18033688011112042f

// ---- async global->LDS, 16B per lane. lds_base must be wave-uniform; HW
// writes lane i's data at lds_base + i*16 (guide §5 caveat).
__device__ __forceinline__ void gld_lds16(const void* g, void* lds_base) {
    __builtin_amdgcn_global_load_lds(
        (const __attribute__((address_space(1))) void*)g,
        (__attribute__((address_space(3))) void*)lds_base, 16, 0, 0);
}

// ============= prep: transpose+cast 4 weights (z<4) | cast x (z==4) ==========
// All global stores vectorized: 16B for x-cast, 8B for the transpose.
__global__ void prep_kernel(const float* __restrict__ x,
                            const float* __restrict__ W0, const float* __restrict__ W1,
                            const float* __restrict__ W2, const float* __restrict__ W3,
                            bf16* __restrict__ xb, bf16* __restrict__ Wt) {
    int tx = threadIdx.x, ty = threadIdx.y;   // (32, 8)
    if (blockIdx.z == 4) {
        // cast x: 1024 blocks x 4096 elems; each thread 16 contiguous elems
        int tid = ty * 32 + tx;
        size_t base = ((size_t)blockIdx.y * 32 + blockIdx.x) * 4096 + (size_t)tid * 16;
        f32x4 v0 = *(const f32x4*)(x + base);
        f32x4 v1 = *(const f32x4*)(x + base + 4);
        f32x4 v2 = *(const f32x4*)(x + base + 8);
        f32x4 v3 = *(const f32x4*)(x + base + 12);
        bf16x8 o0, o1;
#pragma unroll
        for (int r = 0; r < 4; r++) {
            o0[r] = (bf16)v0[r]; o0[r + 4] = (bf16)v1[r];
            o1[r] = (bf16)v2[r]; o1[r + 4] = (bf16)v3[r];
        }
        *(bf16x8*)(xb + base)     = o0;
        *(bf16x8*)(xb + base + 8) = o1;
        return;
    }
    __shared__ float tile[32][33];
    const float* W = (blockIdx.z == 0) ? W0 : (blockIdx.z == 1) ? W1
                   : (blockIdx.z == 2) ? W2 : W3;
    int n0 = blockIdx.x * 32, k0 = blockIdx.y * 32;
#pragma unroll
    for (int j = 0; j < 4; j++)
        tile[ty + 8 * j][tx] = W[(size_t)(k0 + ty + 8 * j) * D_MODEL + n0 + tx];
    __syncthreads();
    bf16* out = Wt + (size_t)blockIdx.z * D_MODEL * D_MODEL;
    // each thread: one 8B store (4 consecutive k) of row n
    int nn = ty + 8 * (tx >> 3);
    int k4 = (tx & 7) * 4;
    bf16x4 pk;
#pragma unroll
    for (int r = 0; r < 4; r++) pk[r] = (bf16)tile[k4 + r][nn];
    *(bf16x4*)(out + (size_t)(n0 + nn) * D_MODEL + k0 + k4) = pk;
}

// ===================== GEMM: C[M,N] = A[M,K] @ Bt[N,K]^T + bias ==============
// m97 base + fine-vmcnt pipeline: triple-buffered LDS, prefetch depth 2,
// raw "s_waitcnt vmcnt(4); s_barrier" -> each wave waits only its own K-slab
// loads; the newest prefetch stays in flight across the barrier.
// launch_bounds(256,3): cap VGPR so LDS(48KB) x 3 = 3 blocks/CU co-resident.
template <int MODE>
__global__ __launch_bounds__(256, 3) void gemm_kernel(
    const bf16* __restrict__ A, const bf16* __restrict__ Bt,
    const float* __restrict__ b0, const float* __restrict__ b1, const float* __restrict__ b2,
    bf16* __restrict__ Qo, bf16* __restrict__ Ko, bf16* __restrict__ Vto,
    float* __restrict__ Co) {
    __shared__ bf16 sA[3][128 * 32];
    __shared__ bf16 sB[3][128 * 32];
    const int t = threadIdx.x;
    const int wave = t >> 6, lane = t & 63;
    const int wm = wave >> 1, wn = wave & 1;
    const int quad = lane >> 4, m16 = lane & 15;
    const int row0 = blockIdx.y * 128, col0 = blockIdx.x * 128;
    const int K = D_MODEL;
    const int NT = K / 32;   // 32 K-slabs

    f32x4 acc[4][4];
#pragma unroll
    for (int i = 0; i < 4; i++)
#pragma unroll
        for (int j = 0; j < 4; j++) acc[i][j] = (f32x4){0.f, 0.f, 0.f, 0.f};

    // stage K-slab j into buffer buf: 4 VMEM instrs per wave
    auto stage = [&](int j, int buf) {
#pragma unroll
        for (int i = 0; i < 2; i++) {
            int cb = i * 256 + wave * 64;       // wave-uniform chunk base
            int c  = cb + lane;                 // this lane's 16B chunk
            int r  = c >> 2, kg = c & 3;        // tile row, k-group
            gld_lds16(A  + (size_t)(row0 + r) * K + j * 32 + kg * 8,
                      (char*)&sA[buf][0] + cb * 16);
            gld_lds16(Bt + (size_t)(col0 + r) * K + j * 32 + kg * 8,
                      (char*)&sB[buf][0] + cb * 16);
        }
    };

    stage(0, 0);
    stage(1, 1);

    for (int j = 0; j < NT; ++j) {
        // wait own slab-j loads (leave newest prefetch in flight), then barrier
        if (j + 1 < NT) asm volatile("s_waitcnt vmcnt(4)\n\ts_barrier" ::: "memory");
        else            asm volatile("s_waitcnt vmcnt(0)\n\ts_barrier" ::: "memory");
        if (j + 2 < NT) stage(j + 2, (j + 2) % 3);   // buffer freed by barrier above
        const int cur = j % 3;

        bf16x8 af[4], bfr[4];
#pragma unroll
        for (int mi = 0; mi < 4; mi++)
            af[mi] = *(const bf16x8*)&sA[cur][(wm * 64 + mi * 16 + m16) * 32 + quad * 8];
#pragma unroll
        for (int ni = 0; ni < 4; ni++)
            bfr[ni] = *(const bf16x8*)&sB[cur][(wn * 64 + ni * 16 + m16) * 32 + quad * 8];
#pragma unroll
        for (int mi = 0; mi < 4; mi++)
#pragma unroll
            for (int ni = 0; ni < 4; ni++)
                acc[mi][ni] = __builtin_amdgcn_mfma_f32_16x16x32_bf16(
                    af[mi], bfr[ni], acc[mi][ni], 0, 0, 0);
    }

    // epilogue. C/D layout: col = lane&15, row = quad*4 + reg (m89-verified).
    if (MODE == 1) {
#pragma unroll
        for (int mi = 0; mi < 4; mi++) {
            int r0 = row0 + wm * 64 + mi * 16 + quad * 4;
#pragma unroll
            for (int ni = 0; ni < 4; ni++) {
                int col = col0 + wn * 64 + ni * 16 + m16;
                float bias = b0[col];
#pragma unroll
                for (int r = 0; r < 4; r++)
                    Co[(size_t)(r0 + r) * D_MODEL + col] = acc[mi][ni][r] + bias;
            }
        }
    } else {
        int sel = col0 >> 10;   // uniform per block (1024 % 128 == 0)
        const float* bias_arr = (sel == 0) ? b0 : (sel == 1) ? b1 : b2;
#pragma unroll
        for (int mi = 0; mi < 4; mi++) {
            int s0g = row0 + wm * 64 + mi * 16 + quad * 4;   // global M-row base
            int b = s0g >> 11, ss0 = s0g & 2047;
#pragma unroll
            for (int ni = 0; ni < 4; ni++) {
                int col = col0 + wn * 64 + ni * 16 + m16;
                int cn = col & 1023;
                int h = cn >> 6, d = cn & 63;
                float bias = bias_arr[cn];
                if (sel < 2) {
                    bf16* dst = (sel == 0) ? Qo : Ko;
                    float scl = (sel == 0) ? QSCALE : 1.0f;
                    size_t base = (((size_t)b * NHEAD + h) * S_LEN);
#pragma unroll
                    for (int r = 0; r < 4; r++)
                        dst[(base + ss0 + r) * DHEAD + d] = (bf16)((acc[mi][ni][r] + bias) * scl);
                } else {
                    bf16x4 pk;
#pragma unroll
                    for (int r = 0; r < 4; r++) pk[r] = (bf16)(acc[mi][ni][r] + bias);
                    *(bf16x4*)(Vto + (((size_t)b * NHEAD + h) * DHEAD + d) * S_LEN + ss0) = pk;
                }
            }
        }
    }
}

// ======================= flash attention (causal) ============================
// R4 structure (best measured: 46.2 µs). One block per (b,h, q-tile PAIR
// {p, 31-p}); the pair shares ONE KV stream -> every block does exactly 33
// weighted tile-iterations (perfect balance). Triple-buffered KV, prefetch
// depth 2, raw s_barrier + s_waitcnt vmcnt(4). Per-wave per-item P buffers;
// item MFMAs interleaved for ILP. Transposed scores (q = lane&15) ->
// per-lane softmax, no running max, l reduced once at the end.
__global__ __launch_bounds__(256, 2) void attn_kernel(
    const bf16* __restrict__ Q, const bf16* __restrict__ K,
    const bf16* __restrict__ Vt, bf16* __restrict__ ctx) {
    __shared__ bf16 Kt_s[3][64 * 64];
    __shared__ bf16 Vt_s[3][64 * 64];
    __shared__ bf16 P_s[4][2][16 * 72];   // per-wave, per-item P[q=16][kpos=64]

    const int t = threadIdx.x, wave = t >> 6, lane = t & 63;
    const int quad = lane >> 4, m16 = lane & 15;
    const int bh = blockIdx.y, p = blockIdx.x;    // pair index 0..15
    const int tT[2] = {p, 31 - p};                // item q-tiles (64 rows each)
    const int nt = 32 - p;                        // shared KV tiles (64-wide)
    const size_t base = (size_t)bh * S_LEN * DHEAD;

    // Q fragments (B-operand) for both items, kept in regs
    bf16x8 aq[2][2];
#pragma unroll
    for (int it = 0; it < 2; it++)
#pragma unroll
        for (int kst = 0; kst < 2; kst++)
            aq[it][kst] = *(const bf16x8*)(Q + base
                + (size_t)(tT[it] * 64 + wave * 16 + m16) * DHEAD + kst * 32 + quad * 8);

    f32x4 o[2][4];
#pragma unroll
    for (int it = 0; it < 2; it++)
#pragma unroll
        for (int di = 0; di < 4; di++) o[it][di] = (f32x4){0.f, 0.f, 0.f, 0.f};
    float l_acc[2] = {0.f, 0.f};

    // stage KV tile j into buffer buf (XOR chunk swizzle vs bank conflicts)
    auto stage = [&](int j, int buf) {
#pragma unroll
        for (int i = 0; i < 2; i++) {
            int cb = i * 256 + wave * 64;
            int c  = cb + lane;
            int pos = c >> 3, g = c & 7;
            int gk = g ^ (pos & 7);
            gld_lds16(K  + base + (size_t)(j * 64 + pos) * DHEAD + gk * 8,
                      (char*)&Kt_s[buf][0] + cb * 16);
            gld_lds16(Vt + base + (size_t)pos * S_LEN + j * 64 + gk * 8,
                      (char*)&Vt_s[buf][0] + cb * 16);
        }
    };

    stage(0, 0);
    if (nt > 1) stage(1, 1);

    for (int j = 0; j < nt; ++j) {
        // wait own tile-j loads (leave newest prefetch in flight), then barrier
        if (j + 1 < nt) asm volatile("s_waitcnt vmcnt(4)\n\ts_barrier" ::: "memory");
        else            asm volatile("s_waitcnt vmcnt(0)\n\ts_barrier" ::: "memory");
        if (j + 2 < nt) stage(j + 2, (j + 2) % 3);   // buffer freed by barrier above

        const int cur = j % 3;
        const bool aAct = (j <= tT[0]);   // item0 still inside its causal prefix
        const int kt0 = j * 64;

        auto computeTile = [&](bool both) {
            int itlo = both ? 0 : 1;
            // ---- scores S^T[kpos][q] = K @ Q^T
            f32x4 sc[2][4];
#pragma unroll
            for (int it = 0; it < 2; it++)
#pragma unroll
                for (int ni = 0; ni < 4; ni++) sc[it][ni] = (f32x4){0.f, 0.f, 0.f, 0.f};
#pragma unroll
            for (int ni = 0; ni < 4; ni++) {
                int pos = ni * 16 + m16;
#pragma unroll
                for (int kst = 0; kst < 2; kst++) {
                    int gg = (kst * 4 + quad) ^ (pos & 7);
                    bf16x8 kf = *(const bf16x8*)&Kt_s[cur][pos * 64 + gg * 8];
                    sc[1][ni] = __builtin_amdgcn_mfma_f32_16x16x32_bf16(
                        kf, aq[1][kst], sc[1][ni], 0, 0, 0);
                    if (both)
                        sc[0][ni] = __builtin_amdgcn_mfma_f32_16x16x32_bf16(
                            kf, aq[0][kst], sc[0][ni], 0, 0, 0);
                }
            }
            // ---- causal mask: only on an item's diagonal tile
#pragma unroll
            for (int it = 0; it < 2; it++) {
                if (it < itlo) continue;
                if (j == tT[it]) {
                    int qg = tT[it] * 64 + wave * 16 + m16;
#pragma unroll
                    for (int ni = 0; ni < 4; ni++)
#pragma unroll
                        for (int r = 0; r < 4; r++) {
                            int kp = kt0 + ni * 16 + quad * 4 + r;
                            if (kp > qg) sc[it][ni][r] = -1e9f;
                        }
                }
            }
            // ---- p = exp2(s); accumulate l; write P (wave-local LDS)
#pragma unroll
            for (int it = 0; it < 2; it++) {
                if (it < itlo) continue;
                bf16* Pw = &P_s[wave][it][0];
                float ls = 0.f;
#pragma unroll
                for (int ni = 0; ni < 4; ni++) {
                    bf16x4 pk;
#pragma unroll
                    for (int r = 0; r < 4; r++) {
                        float pe = __builtin_amdgcn_exp2f(sc[it][ni][r]);
                        ls += pe;
                        pk[r] = (bf16)pe;
                    }
                    *(bf16x4*)&Pw[m16 * 72 + ni * 16 + quad * 4] = pk;
                }
                l_acc[it] += ls;
            }
            // ---- O^T += (P @ V)^T = mfma(A=V^T frag, B=P frag)
#pragma unroll
            for (int kst = 0; kst < 2; kst++) {
                bf16x8 ap[2];
#pragma unroll
                for (int it = 0; it < 2; it++)
                    if (it >= itlo)
                        ap[it] = *(const bf16x8*)&P_s[wave][it][m16 * 72 + kst * 32 + quad * 8];
#pragma unroll
                for (int di = 0; di < 4; di++) {
                    int d = di * 16 + m16;
                    int gg = (kst * 4 + quad) ^ (d & 7);
                    bf16x8 vf = *(const bf16x8*)&Vt_s[cur][d * 64 + gg * 8];
                    o[1][di] = __builtin_amdgcn_mfma_f32_16x16x32_bf16(
                        vf, ap[1], o[1][di], 0, 0, 0);
                    if (both)
                        o[0][di] = __builtin_amdgcn_mfma_f32_16x16x32_bf16(
                            vf, ap[0], o[0][di], 0, 0, 0);
                }
            }
        };
        if (aAct) computeTile(true);
        else      computeTile(false);
    }

    // ---- final l reduction + normalize + write ctx [B,S,1024] bf16
    int b = bh >> 4, h = bh & 15;
#pragma unroll
    for (int it = 0; it < 2; it++) {
        float l = l_acc[it];
        l += __shfl_xor(l, 16);
        l += __shfl_xor(l, 32);
        float rl = 1.0f / l;
        int s = tT[it] * 64 + wave * 16 + m16;
#pragma unroll
        for (int di = 0; di < 4; di++) {
            bf16x4 pk;
#pragma unroll
            for (int r = 0; r < 4; r++) pk[r] = (bf16)(o[it][di][r] * rl);
            *(bf16x4*)(ctx + ((size_t)b * S_LEN + s) * D_MODEL
                       + h * DHEAD + di * 16 + quad * 4) = pk;
        }
    }
}

// ================================ launch =====================================
extern "C" void kernel_launch(void* const* d_in, const int* in_sizes, int n_in,
                              void* d_out, int out_size, void* d_ws, size_t ws_size,
                              hipStream_t stream) {
    const float* x  = (const float*)d_in[0];
    const float* Wq = (const float*)d_in[1];
    const float* bq = (const float*)d_in[2];
    const float* Wk = (const float*)d_in[3];
    const float* bk = (const float*)d_in[4];
    const float* Wv = (const float*)d_in[5];
    const float* bv = (const float*)d_in[6];
    const float* Wo = (const float*)d_in[7];
    const float* bo = (const float*)d_in[8];
    float* out = (float*)d_out;

    char* ws = (char*)d_ws;
    const size_t MB = 1u << 20;
    bf16* xb  = (bf16*)(ws + 0);         // 8 MB  [4096,1024]
    bf16* Wt  = (bf16*)(ws + 8  * MB);   // 8 MB  [4][1024][1024]
    bf16* Qb  = (bf16*)(ws + 16 * MB);   // 8 MB  [B,H,S,64]  (pre-scaled by QSCALE)
    bf16* Kb  = (bf16*)(ws + 24 * MB);   // 8 MB  [B,H,S,64]
    bf16* Vtb = (bf16*)(ws + 32 * MB);   // 8 MB  [B,H,64,S]
    bf16* ctx = (bf16*)(ws + 0);         // reuse xb region (dead after QKV GEMM)

    prep_kernel<<<dim3(32, 32, 5), dim3(32, 8), 0, stream>>>(x, Wq, Wk, Wv, Wo, xb, Wt);
    gemm_kernel<0><<<dim3(24, 32), 256, 0, stream>>>(xb, Wt, bq, bk, bv,
                                                     Qb, Kb, Vtb, nullptr);
    attn_kernel<<<dim3(16, 32), 256, 0, stream>>>(Qb, Kb, Vtb, ctx);
    gemm_kernel<1><<<dim3(8, 32), 256, 0, stream>>>(ctx, Wt + 3 * 1024 * 1024,
                                                    bo, nullptr, nullptr,
                                                    nullptr, nullptr, nullptr, out);
}